// Round 1
// baseline (507.658 us; speedup 1.0000x reference)
//
#include <hip/hip_runtime.h>
#include <math.h>

#define HIDDEN    1024
#define NEXP      64
#define MTILE     64
#define KSTEP     64

// ws layout (floats)
#define WT_OFF 0        // Wt[k][e] : 1024*64
#define QL_OFF 65536    // qry_logits[b][e] : 8*64

// out layout (floats), return order: topk_scores, topk_idx, gate_scores, gate_logits
#define OUT_TKS 0
#define OUT_TKI 147456
#define OUT_GS  294912
#define OUT_GL  5013504

typedef const __attribute__((address_space(1))) void* gas_p;
typedef __attribute__((address_space(3))) void* las_p;

__device__ __forceinline__ void g2lds16(const float* g, float* l) {
  __builtin_amdgcn_global_load_lds((gas_p)(const void*)g, (las_p)(void*)l, 16, 0, 0);
}

// blocks 0..255: transpose W_vis -> Wt[k][e]; blocks 256..263: qry logits
__global__ __launch_bounds__(256) void prep_kernel(
    const float* __restrict__ query_emb, const float* __restrict__ W_gate,
    float* __restrict__ ws) {
  const int bid = blockIdx.x;
  const int tid = threadIdx.x;
  if (bid < 256) {
    const int idx = bid * 256 + tid;       // 0..65535
    const int k = idx >> 6, e = idx & 63;
    ws[WT_OFF + idx] = W_gate[e * 2048 + k];
  } else {
    const int b = bid - 256;               // 0..7
    const int e = tid >> 2, q = tid & 3;   // expert, quarter of K
    const float* qp = query_emb + b * 1024 + q * 256;
    const float* wp = W_gate + e * 2048 + 1024 + q * 256;
    float s = 0.f;
    #pragma unroll 4
    for (int j = 0; j < 256; j += 4) {
      const float4 a = *(const float4*)(qp + j);
      const float4 w = *(const float4*)(wp + j);
      s += a.x * w.x + a.y * w.y + a.z * w.z + a.w * w.w;
    }
    s += __shfl_xor(s, 1);
    s += __shfl_xor(s, 2);
    if (q == 0) ws[QL_OFF + b * 64 + e] = s;
  }
}

__global__ __launch_bounds__(256) void router_main(
    const float* __restrict__ vis, const float* __restrict__ ws,
    float* __restrict__ out) {
  // As: k-major, column-swizzled: element (k,t) at word k*64 + (t ^ (4*(k>>2)))
  __shared__ __align__(16) float As[KSTEP * 64];
  __shared__ __align__(16) float Ws[KSTEP * 64];   // [k][e], linear
  const int tid = threadIdx.x;
  const int tx = tid & 15, ty = tid >> 4;          // experts 4*tx.., tokens 4*ty..
  const int lane = tid & 63, wv = tid >> 6;
  const long base = (long)blockIdx.x * MTILE;      // 576 = 9*64 -> block never crosses n
  const float* Wt = ws + WT_OFF;

  float acc[4][4] = {};

  for (int k0 = 0; k0 < HIDDEN; k0 += KSTEP) {
    __syncthreads();
    // --- W tile: 16KB contiguous from Wt + k0*64, direct-to-LDS ---
    {
      const float* gw = Wt + k0 * 64 + wv * 1024 + lane * 4;
      float* lw = &Ws[wv * 1024];
      #pragma unroll
      for (int c = 0; c < 4; ++c)
        g2lds16(gw + c * 256, lw + c * 256);
    }
    // --- A tile: coalesced float4 global read, swizzled scalar LDS transpose ---
    #pragma unroll
    for (int p = 0; p < 4; ++p) {
      const int ii = p * 256 + tid;
      const int t = ii >> 4, kg = ii & 15;         // token, k-group (of 4)
      const float4 v = *(const float4*)(vis + (base + t) * 1024 + k0 + kg * 4);
      const int w0 = kg * 256 + (t ^ (kg * 4));    // (4*kg+j)*64 + swizzled col
      As[w0]       = v.x;
      As[w0 + 64]  = v.y;
      As[w0 + 128] = v.z;
      As[w0 + 192] = v.w;
    }
    __syncthreads();
    // --- inner product: 2x ds_read_b128 + 16 FMA per k ---
    #pragma unroll 8
    for (int k = 0; k < KSTEP; ++k) {
      const float4 a = *(const float4*)&As[k * 64 + ((ty * 4) ^ ((k >> 2) * 4))];
      const float4 b = *(const float4*)&Ws[k * 64 + tx * 4];
      acc[0][0] += a.x * b.x; acc[0][1] += a.x * b.y; acc[0][2] += a.x * b.z; acc[0][3] += a.x * b.w;
      acc[1][0] += a.y * b.x; acc[1][1] += a.y * b.y; acc[1][2] += a.y * b.z; acc[1][3] += a.y * b.w;
      acc[2][0] += a.z * b.x; acc[2][1] += a.z * b.y; acc[2][2] += a.z * b.z; acc[2][3] += a.z * b.w;
      acc[3][0] += a.w * b.x; acc[3][1] += a.w * b.y; acc[3][2] += a.w * b.z; acc[3][3] += a.w * b.w;
    }
  }

  // --- epilogue: qry add, logits, softmax, top-2 ---
  const int bq = (int)(base / 9216);               // (token/576)/16, block-uniform
  const float4 qv = *(const float4*)(ws + QL_OFF + bq * 64 + tx * 4);

  float* out_tks = out + OUT_TKS;
  float* out_tki = out + OUT_TKI;
  float* out_gs  = out + OUT_GS;
  float* out_gl  = out + OUT_GL;

  #pragma unroll
  for (int i = 0; i < 4; ++i) {
    const long tok = base + ty * 4 + i;
    const float l0 = acc[i][0] + qv.x;
    const float l1 = acc[i][1] + qv.y;
    const float l2 = acc[i][2] + qv.z;
    const float l3 = acc[i][3] + qv.w;
    *(float4*)(out_gl + tok * 64 + tx * 4) = make_float4(l0, l1, l2, l3);

    float m = fmaxf(fmaxf(l0, l1), fmaxf(l2, l3));
    #pragma unroll
    for (int msk = 1; msk < 16; msk <<= 1) m = fmaxf(m, __shfl_xor(m, msk));

    const float e0 = expf(l0 - m), e1 = expf(l1 - m), e2 = expf(l2 - m), e3 = expf(l3 - m);
    float ssum = e0 + e1 + e2 + e3;
    #pragma unroll
    for (int msk = 1; msk < 16; msk <<= 1) ssum += __shfl_xor(ssum, msk);
    const float inv = 1.0f / ssum;
    const float s0 = e0 * inv, s1 = e1 * inv, s2 = e2 * inv, s3 = e3 * inv;
    *(float4*)(out_gs + tok * 64 + tx * 4) = make_float4(s0, s1, s2, s3);

    // local top-2 (ascending idx + strict '>' => lowest index wins ties, jax semantics)
    float v1 = s0, v2 = s1; int i1 = tx * 4, i2 = tx * 4 + 1;
    if (s1 > v1) { v2 = v1; i2 = i1; v1 = s1; i1 = tx * 4 + 1; }
    if (s2 > v1)      { v2 = v1; i2 = i1; v1 = s2; i1 = tx * 4 + 2; }
    else if (s2 > v2) { v2 = s2; i2 = tx * 4 + 2; }
    if (s3 > v1)      { v2 = v1; i2 = i1; v1 = s3; i1 = tx * 4 + 3; }
    else if (s3 > v2) { v2 = s3; i2 = tx * 4 + 3; }

    // 16-lane butterfly merge of sorted top-2 lists
    #pragma unroll
    for (int msk = 1; msk < 16; msk <<= 1) {
      const float w1 = __shfl_xor(v1, msk), w2 = __shfl_xor(v2, msk);
      const int   j1 = __shfl_xor(i1, msk), j2 = __shfl_xor(i2, msk);
      const bool wfirst = (w1 > v1) || (w1 == v1 && j1 < i1);
      if (wfirst) {
        const bool vsec = (v1 > w2) || (v1 == w2 && i1 < j2);
        v2 = vsec ? v1 : w2; i2 = vsec ? i1 : j2;
        v1 = w1; i1 = j1;
      } else {
        const bool wsec = (w1 > v2) || (w1 == v2 && j1 < i2);
        if (wsec) { v2 = w1; i2 = j1; }
      }
    }
    if (tx == 0) {
      *(float2*)(out_tks + tok * 2) = make_float2(v1, v2);
      *(float2*)(out_tki + tok * 2) = make_float2((float)i1, (float)i2);
    }
  }
}

extern "C" void kernel_launch(void* const* d_in, const int* in_sizes, int n_in,
                              void* d_out, int out_size, void* d_ws, size_t ws_size,
                              hipStream_t stream) {
  const float* vis   = (const float*)d_in[0];
  const float* query = (const float*)d_in[1];
  const float* wg    = (const float*)d_in[2];
  float* ws  = (float*)d_ws;
  float* o   = (float*)d_out;
  hipLaunchKernelGGL(prep_kernel, dim3(264), dim3(256), 0, stream, query, wg, ws);
  hipLaunchKernelGGL(router_main, dim3(1152), dim3(256), 0, stream, vis, ws, o);
}